// Round 8
// baseline (23468.672 us; speedup 1.0000x reference)
//
#include <hip/hip_runtime.h>
#include <hip/hip_bf16.h>

// LSTMModel_with_theta: B=64, T=2048, H=256, 2-layer LSTM -> mean_t -> MLP.
//
// Round 8: 2-way batch-group interleave to HIDE the MALL exchange latency.
//  - r7 post-mortem: no spill (bw lives in AGPRs; VGPR_Count excludes AGPRs);
//    4.8us/step = exposed agent-atomic RTT (~700-900cy) + first-poll miss +
//    retry quantization + 10-WG jitter. Compute is only ~2K cy/step.
//  - Fix: each WG runs TWO independent batch-group chains (groups {0,1} or
//    {2,3}). Same weight registers serve both chains (weights are shared
//    across batch!); only cL/hs/acc duplicate. Chain A's staging loads are
//    issued at the end of A's sub-step and consumed one sub-step later
//    (~1.3K cy > RTT) -> prefetch hides the fabric hop; retries vanish.
//  - 20 WGs total (L0: 4 = 2 pair-sets x 2 halves; L1: 16 = 2 x 8 octants).
//  - Sync semantics unchanged from r7: tagged u32 (tag=t+1)<<16|bf16, relaxed
//    agent atomics only, s_barrier+lgkmcnt barriers (no vmcnt drains in-loop).
//  - Rings memset each launch (removes cross-launch stale-tag aliasing).

#define BB 64
#define TT 2048
#define HH 256
#define D0 16
#define D1 4

typedef short s16x8 __attribute__((ext_vector_type(8)));
typedef float f32x4 __attribute__((ext_vector_type(4)));

__device__ inline unsigned short f2bf(float f) {
  unsigned u = __float_as_uint(f);
  u += 0x7fff + ((u >> 16) & 1);          // RNE
  return (unsigned short)(u >> 16);
}
__device__ inline float sigm(float x) { return 1.f / (1.f + __expf(-x)); }
__device__ inline float tanh_f(float x) { return 1.f - 2.f / (__expf(2.f * x) + 1.f); }

__device__ inline unsigned long long ld64(const unsigned int* p) {
  return __hip_atomic_load((const unsigned long long*)p, __ATOMIC_RELAXED,
                           __HIP_MEMORY_SCOPE_AGENT);
}
__device__ inline void st32(unsigned int* p, unsigned int v) {
  __hip_atomic_store(p, v, __ATOMIC_RELAXED, __HIP_MEMORY_SCOPE_AGENT);
}
__device__ inline void st32i(int* p, int v) {
  __hip_atomic_store(p, v, __ATOMIC_RELAXED, __HIP_MEMORY_SCOPE_AGENT);
}
__device__ inline int ld32i(const int* p) {
  return __hip_atomic_load(p, __ATOMIC_RELAXED, __HIP_MEMORY_SCOPE_AGENT);
}
// barrier WITHOUT vmcnt drain: LDS-fence only (global tagged stores fly free)
__device__ inline void wg_bar() {
  asm volatile("s_waitcnt lgkmcnt(0)" ::: "memory");
  __builtin_amdgcn_sched_barrier(0);
  __builtin_amdgcn_s_barrier();
  __builtin_amdgcn_sched_barrier(0);
}

#define MFMA(a, b, c) __builtin_amdgcn_mfma_f32_16x16x32_bf16((a), (b), (c), 0, 0, 0)

__global__ void xt_kernel(const float* __restrict__ x, float* __restrict__ xT) {
  int i = blockIdx.x * 256 + threadIdx.x;   // 131072 total
  int b = i & 63, t = i >> 6;
  xT[(size_t)t * BB + b] = x[(size_t)b * TT + t];
}

__global__ __launch_bounds__(512, 1)
void lstm_kernel(const float* __restrict__ Wx0, const float* __restrict__ Wh0,
                 const float* __restrict__ b0v,
                 const float* __restrict__ Wx1, const float* __restrict__ Wh1,
                 const float* __restrict__ b1v,
                 const float* __restrict__ xT,
                 unsigned int* __restrict__ seqring,   // [4][D0][16][256] tagged u32
                 unsigned int* __restrict__ h1ring,    // [4][D1][16][256] tagged u32
                 float* __restrict__ hmean, int* prog)
{
  __shared__ __align__(16) char smem[16384];   // L0: 2 x 8KB per-chain h-tile; L1: Ab|Ab1

  const int tid  = threadIdx.x;
  const int lane = tid & 63;
  const int w    = tid >> 6;        // wave 0..7
  const int u16  = lane & 15;
  const int kgrp = lane >> 4;
  const int arow = lane & 15;
  const int bid  = blockIdx.x;

  if (bid < 4) {
    // ========== LAYER 0: 2 WGs per pair-set (halves), 2 chains each ==========
    const int ps = bid >> 1, ho = bid & 1, po = 1 - ho;
    const int U = ho * 128 + w * 16 + u16;       // lane's unit (owns all 4 gates)
    s16x8 bw[32];                                // [gate*8 + ks(abs)] : 128 AGPR/VGPR
#pragma unroll
    for (int n = 0; n < 4; ++n)
#pragma unroll
      for (int ks = 0; ks < 8; ++ks) {
        const int col = n * 256 + U;
#pragma unroll
        for (int j = 0; j < 8; ++j)
          bw[n * 8 + ks][j] = (short)f2bf(Wh0[(size_t)(ks * 32 + kgrp * 8 + j) * 1024 + col]);
      }
    float bE[4], xE[4];
#pragma unroll
    for (int n = 0; n < 4; ++n) { bE[n] = b0v[n * 256 + U]; xE[n] = Wx0[n * 256 + U]; }

    const int srow = tid >> 5, spc = (tid & 31) * 4;   // stage: 16B/thread
    unsigned int* srg[2];
#pragma unroll
    for (int c = 0; c < 2; ++c) srg[c] = seqring + (size_t)(ps * 2 + c) * D0 * 4096;
    float cL[2][4] = {{0.f,0.f,0.f,0.f},{0.f,0.f,0.f,0.f}};
    unsigned long long pq[2][2];                 // in-flight partner loads per chain

    for (int t = 0; t < TT; ++t) {
#pragma unroll
      for (int c = 0; c < 2; ++c) {
        const int g = ps * 2 + c;
        if ((t & 7) == 0 && t >= 16 && tid < 8) {      // L1 back-pressure (coarse)
          const int need = t - 8;
          while (ld32i(&prog[(g * 8 + tid) * 16]) < need) __builtin_amdgcn_s_sleep(8);
        }
        char* Abc = smem + c * 8192;
        if (t > 0) {
          // tag-check prefetched partner h(t-1); steady state: first check passes
          const unsigned int* sb = srg[c] + ((t - 1) & (D0 - 1)) * 4096 + srow * 256 + po * 128 + spc;
          unsigned long long q0 = pq[c][0], q1 = pq[c][1];
          const unsigned int tg = (unsigned int)t;
          for (;;) {
            const bool ok = (((q0 >> 16) & 0xFFFFu) == tg) & ((unsigned)(q0 >> 48) == tg) &
                            (((q1 >> 16) & 0xFFFFu) == tg) & ((unsigned)(q1 >> 48) == tg);
            if (__all(ok)) break;
            __builtin_amdgcn_s_sleep(1);
            q0 = ld64(sb); q1 = ld64(sb + 2);
          }
          const unsigned int lo = (unsigned)(q0 & 0xFFFF) | (((unsigned)(q0 >> 32) & 0xFFFF) << 16);
          const unsigned int hi = (unsigned)(q1 & 0xFFFF) | (((unsigned)(q1 >> 32) & 0xFFFF) << 16);
          *(uint2*)(Abc + ((srow * 512 + (po * 128 + spc) * 2) ^ ((srow & 7) << 4))) = (uint2){lo, hi};
        }
        wg_bar();                                      // staging visible to all waves

        f32x4 acc[4] = {{0,0,0,0},{0,0,0,0},{0,0,0,0},{0,0,0,0}};
        if (t > 0) {
#pragma unroll
          for (int b2 = 0; b2 < 2; ++b2) {             // 2 batches of 4 frags (caps live regs)
            s16x8 a[4];
#pragma unroll
            for (int i = 0; i < 4; ++i) {
              const int ks = b2 * 4 + i;
              a[i] = *(const s16x8*)(Abc + ((arow * 512 + (ks * 32 + kgrp * 8) * 2) ^ ((arow & 7) << 4)));
            }
#pragma unroll
            for (int i = 0; i < 4; ++i)
#pragma unroll
              for (int n = 0; n < 4; ++n) acc[n] = MFMA(a[i], bw[n * 8 + b2 * 4 + i], acc[n]);
          }
        }
        // EW fully per-lane; publish tagged + own-h to LDS
        float xr[4];
#pragma unroll
        for (int r = 0; r < 4; ++r) xr[r] = xT[(size_t)t * BB + g * 16 + kgrp * 4 + r];
        const unsigned int tagw = (unsigned)(t + 1) << 16;
#pragma unroll
        for (int r = 0; r < 4; ++r) {
          const int row = kgrp * 4 + r;
          const float gi = acc[0][r] + bE[0] + xr[r] * xE[0];
          const float gf = acc[1][r] + bE[1] + xr[r] * xE[1];
          const float gg = acc[2][r] + bE[2] + xr[r] * xE[2];
          const float go = acc[3][r] + bE[3] + xr[r] * xE[3];
          cL[c][r] = sigm(gf) * cL[c][r] + sigm(gi) * tanh_f(gg);
          const float hv = sigm(go) * tanh_f(cL[c][r]);
          const unsigned short hb = f2bf(hv);
          st32(srg[c] + (t & (D0 - 1)) * 4096 + row * 256 + U, tagw | hb);
          *(unsigned short*)(Abc + ((row * 512 + U * 2) ^ ((row & 7) << 4))) = hb;
        }
        // prefetch partner h(t) for next superstep (flies during other chain's sub-step)
        {
          const unsigned int* sb = srg[c] + (t & (D0 - 1)) * 4096 + srow * 256 + po * 128 + spc;
          pq[c][0] = ld64(sb); pq[c][1] = ld64(sb + 2);
        }
      }
    }
  } else {
    // ========== LAYER 1: 8 WGs per pair-set (32-unit octants), 2 chains each ==========
    const int idx = bid - 4, ps = idx >> 3, q = idx & 7;
    const int go_ = u16 >> 2;                    // lane's MFMA gate (quad role)
    const int U   = q * 32 + w * 4 + (u16 & 3);  // lane's unit
    s16x8 bw[16];                                // ks<8: Wx1, ks>=8: Wh1
#pragma unroll
    for (int ks = 0; ks < 16; ++ks) {
      const int col = go_ * 256 + U;
#pragma unroll
      for (int j = 0; j < 8; ++j) {
        const int k = (ks & 7) * 32 + kgrp * 8 + j;
        bw[ks][j] = (short)f2bf((ks < 8) ? Wx1[(size_t)k * 1024 + col]
                                         : Wh1[(size_t)k * 1024 + col]);
      }
    }
    float bE[4];
#pragma unroll
    for (int n = 0; n < 4; ++n) bE[n] = b1v[n * 256 + U];

    unsigned int *srg[2], *hrg[2];
#pragma unroll
    for (int c = 0; c < 2; ++c) {
      srg[c] = seqring + (size_t)(ps * 2 + c) * D0 * 4096;
      hrg[c] = h1ring  + (size_t)(ps * 2 + c) * D1 * 4096;
    }
    const int half = w >> 2;                     // waves 0-3: h0 stage; 4-7: h1 stage
    const int st2 = tid & 255;
    const int srow = st2 >> 4, scol = (st2 & 15) * 16;   // 16 tagged u32 / thread
    char* Ab  = smem;                            // h0(t)
    char* Ab1 = smem + 8192;                     // h1(t-1)
    float cL[2][4] = {{0.f,0.f,0.f,0.f},{0.f,0.f,0.f,0.f}};
    float hs[2][4] = {{0.f,0.f,0.f,0.f},{0.f,0.f,0.f,0.f}};
    unsigned long long qv[2][8];                 // in-flight stage loads per chain

    // prologue: prefetch h0(0) for both chains (half0 role)
#pragma unroll
    for (int c = 0; c < 2; ++c)
      if (half == 0) {
        const unsigned int* sb = srg[c] + 0 * 4096 + srow * 256 + scol;
#pragma unroll
        for (int i = 0; i < 8; ++i) qv[c][i] = ld64(sb + i * 2);
      }

    for (int t = 0; t < TT; ++t) {
#pragma unroll
      for (int c = 0; c < 2; ++c) {
        const int g = ps * 2 + c;
        if ((t & 3) == 3 && tid == 0) st32i(&prog[(g * 8 + q) * 16], t);
        // ---- tag-check prefetched data; write into LDS ----
        if (half == 0) {
          const unsigned int* sb = srg[c] + (t & (D0 - 1)) * 4096 + srow * 256 + scol;
          const unsigned int tg = (unsigned int)(t + 1);
          for (;;) {
            bool ok = true;
#pragma unroll
            for (int i = 0; i < 8; ++i)
              ok &= (((qv[c][i] >> 16) & 0xFFFFu) == tg) & ((unsigned)(qv[c][i] >> 48) == tg);
            if (__all(ok)) break;
            __builtin_amdgcn_s_sleep(1);
#pragma unroll
            for (int i = 0; i < 8; ++i) qv[c][i] = ld64(sb + i * 2);
          }
          unsigned int wv[8];
#pragma unroll
          for (int i = 0; i < 8; ++i)
            wv[i] = (unsigned)(qv[c][i] & 0xFFFF) | (((unsigned)(qv[c][i] >> 32) & 0xFFFF) << 16);
          const int ba = srow * 512 + scol * 2;
          *(uint4*)(Ab + ((ba     ) ^ ((srow & 7) << 4))) = (uint4){wv[0], wv[1], wv[2], wv[3]};
          *(uint4*)(Ab + ((ba + 16) ^ ((srow & 7) << 4))) = (uint4){wv[4], wv[5], wv[6], wv[7]};
        } else if (t > 0) {
          const unsigned int* sb = hrg[c] + ((t - 1) & (D1 - 1)) * 4096 + srow * 256 + scol;
          const unsigned int tg = (unsigned int)t;
          for (;;) {
            bool ok = true;
#pragma unroll
            for (int i = 0; i < 8; ++i)
              ok &= (((qv[c][i] >> 16) & 0xFFFFu) == tg) & ((unsigned)(qv[c][i] >> 48) == tg);
            if (__all(ok)) break;
            __builtin_amdgcn_s_sleep(1);
#pragma unroll
            for (int i = 0; i < 8; ++i) qv[c][i] = ld64(sb + i * 2);
          }
          unsigned int wv[8];
#pragma unroll
          for (int i = 0; i < 8; ++i)
            wv[i] = (unsigned)(qv[c][i] & 0xFFFF) | (((unsigned)(qv[c][i] >> 32) & 0xFFFF) << 16);
          const int ba = srow * 512 + scol * 2;
          *(uint4*)(Ab1 + ((ba     ) ^ ((srow & 7) << 4))) = (uint4){wv[0], wv[1], wv[2], wv[3]};
          *(uint4*)(Ab1 + ((ba + 16) ^ ((srow & 7) << 4))) = (uint4){wv[4], wv[5], wv[6], wv[7]};
        }
        wg_bar();                                      // staged -> readable
        f32x4 accA = {0,0,0,0}, accB = {0,0,0,0};
#pragma unroll
        for (int b2 = 0; b2 < 2; ++b2) {
          s16x8 a[4];
#pragma unroll
          for (int i = 0; i < 4; ++i) {
            const int ks = b2 * 4 + i;
            a[i] = *(const s16x8*)(Ab + ((arow * 512 + (ks * 32 + kgrp * 8) * 2) ^ ((arow & 7) << 4)));
          }
#pragma unroll
          for (int i = 0; i < 4; ++i) accA = MFMA(a[i], bw[b2 * 4 + i], accA);
        }
        if (t > 0) {
#pragma unroll
          for (int b2 = 0; b2 < 2; ++b2) {
            s16x8 a[4];
#pragma unroll
            for (int i = 0; i < 4; ++i) {
              const int ks = b2 * 4 + i;
              a[i] = *(const s16x8*)(Ab1 + ((arow * 512 + (ks * 32 + kgrp * 8) * 2) ^ ((arow & 7) << 4)));
            }
#pragma unroll
            for (int i = 0; i < 4; ++i) accB = MFMA(a[i], bw[8 + b2 * 4 + i], accB);
          }
        }
        wg_bar();                                      // Ab/Ab1 free for next chain's staging
        // ---- EW: gather 4 gates via shfl_xor quad exchange ----
        const unsigned int tagw = (unsigned)(t + 1) << 16;
        const bool q0b = go_ & 1, q1b = go_ & 2;
#pragma unroll
        for (int r = 0; r < 4; ++r) {
          const float av = accA[r] + accB[r];
          const float Bv = __shfl_xor(av, 4);
          const float Cv = __shfl_xor(av, 8);
          const float Dv = __shfl_xor(av, 12);
          const float e0 = q0b ? Bv : av,  e1 = q0b ? av : Bv;
          const float f0 = q0b ? Dv : Cv,  f1 = q0b ? Cv : Dv;
          const float gi = (q1b ? f0 : e0) + bE[0];
          const float gf = (q1b ? f1 : e1) + bE[1];
          const float gg = (q1b ? e0 : f0) + bE[2];
          const float go = (q1b ? e1 : f1) + bE[3];
          cL[c][r] = sigm(gf) * cL[c][r] + sigm(gi) * tanh_f(gg);
          const float hv = sigm(go) * tanh_f(cL[c][r]);
          hs[c][r] += hv;
          if (u16 < 4)
            st32(hrg[c] + (t & (D1 - 1)) * 4096 + (kgrp * 4 + r) * 256 + U, tagw | f2bf(hv));
        }
        // ---- prefetch for t+1 (flies during other chain's sub-step) ----
        if (half == 0) {
          const unsigned int* sb = srg[c] + ((t + 1) & (D0 - 1)) * 4096 + srow * 256 + scol;
#pragma unroll
          for (int i = 0; i < 8; ++i) qv[c][i] = ld64(sb + i * 2);
        } else {
          const unsigned int* sb = hrg[c] + (t & (D1 - 1)) * 4096 + srow * 256 + scol;
#pragma unroll
          for (int i = 0; i < 8; ++i) qv[c][i] = ld64(sb + i * 2);
        }
      }
    }
#pragma unroll
    for (int c = 0; c < 2; ++c)
      if (u16 < 4) {
#pragma unroll
        for (int r = 0; r < 4; ++r)
          hmean[(size_t)((ps * 2 + c) * 16 + kgrp * 4 + r) * HH + U] = hs[c][r] * (1.f / TT);
      }
  }
}

__global__ __launch_bounds__(256)
void mlp_kernel(const float* __restrict__ theta, const float* __restrict__ Wtp,
                const float* __restrict__ btp, const float* __restrict__ Wl1,
                const float* __restrict__ bl1, const float* __restrict__ Wl2,
                const float* __restrict__ bl2, const float* __restrict__ Wo,
                const float* __restrict__ bo, const float* __restrict__ hmean,
                float* __restrict__ out)
{
  const int b = blockIdx.x;
  const int j = threadIdx.x;
  __shared__ float z[2 * HH];
  __shared__ float z1s[HH];
  __shared__ float red[256];

  float tp = btp[j];
#pragma unroll
  for (int d = 0; d < 5; ++d) tp += theta[b * 5 + d] * Wtp[d * HH + j];
  z[j] = hmean[(size_t)b * HH + j];
  z[HH + j] = tp;
  __syncthreads();

  float a1 = bl1[j];
  for (int k = 0; k < 2 * HH; ++k) a1 += z[k] * Wl1[(size_t)k * 256 + j];
  a1 = (a1 > 0.f) ? a1 : (__expf(a1) - 1.f);
  z1s[j] = a1;
  __syncthreads();

  float a2 = bl2[j];
  for (int k = 0; k < HH; ++k) a2 += z1s[k] * Wl2[(size_t)k * 256 + j];
  a2 = (a2 > 0.f) ? a2 : (__expf(a2) - 1.f);
  red[j] = a2 * Wo[j];
  __syncthreads();
  for (int s = 128; s > 0; s >>= 1) {
    if (j < s) red[j] += red[j + s];
    __syncthreads();
  }
  if (j == 0) out[b] = red[0] + bo[0];
}

extern "C" void kernel_launch(void* const* d_in, const int* in_sizes, int n_in,
                              void* d_out, int out_size, void* d_ws, size_t ws_size,
                              hipStream_t stream) {
  const float* x    = (const float*)d_in[0];
  const float* theta= (const float*)d_in[1];
  const float* Wx0  = (const float*)d_in[2];
  const float* Wh0  = (const float*)d_in[3];
  const float* b0   = (const float*)d_in[4];
  const float* Wx1  = (const float*)d_in[5];
  const float* Wh1  = (const float*)d_in[6];
  const float* b1   = (const float*)d_in[7];
  const float* Wtp  = (const float*)d_in[8];
  const float* btp  = (const float*)d_in[9];
  const float* Wl1  = (const float*)d_in[10];
  const float* bl1  = (const float*)d_in[11];
  const float* Wl2  = (const float*)d_in[12];
  const float* bl2  = (const float*)d_in[13];
  const float* Wo   = (const float*)d_in[14];
  const float* bo   = (const float*)d_in[15];

  // ws: prog 8KB | seqring u32 [4][16][16][256] 1MB | h1ring u32 [4][4][16][256] 256KB
  //     | hmean f32 64KB | xT f32 512KB
  char* ws = (char*)d_ws;
  int* prog             = (int*)ws;
  unsigned int* seqring = (unsigned int*)(ws + 8192);
  unsigned int* h1ring  = (unsigned int*)(ws + 8192 + 1048576);
  float* hmean          = (float*)(ws + 8192 + 1048576 + 262144);
  float* xT             = (float*)(ws + 8192 + 1048576 + 262144 + 65536);
  const size_t WS_NEED = 8192ull + 1048576 + 262144 + 65536 + 524288;
  if (ws_size < WS_NEED) return;

  // reset prog + BOTH rings (kills cross-launch stale-tag aliasing)
  hipMemsetAsync(d_ws, 0, 8192 + 1048576 + 262144, stream);

  xt_kernel<<<dim3((BB * TT) / 256), dim3(256), 0, stream>>>(x, xT);
  lstm_kernel<<<dim3(20), dim3(512), 0, stream>>>(
      Wx0, Wh0, b0, Wx1, Wh1, b1, xT, seqring, h1ring, hmean, prog);
  mlp_kernel<<<dim3(BB), dim3(256), 0, stream>>>(
      theta, Wtp, btp, Wl1, bl1, Wl2, bl2, Wo, bo, hmean, (float*)d_out);
}

// Round 9
// 8394.110 us; speedup vs baseline: 2.7958x; 2.7958x over previous
//
#include <hip/hip_runtime.h>
#include <hip/hip_bf16.h>

// LSTMModel_with_theta: B=64, T=2048, H=256, 2-layer LSTM -> mean_t -> MLP.
//
// Round 9: r4 semantics (cached broadcast of append-only seq0 + flags),
// restructured topology:
//  - 32 WGs x 512thr. Per batch group (16 rows): L0 = 4 WGs x 64 units (K=256),
//    L1 = 4 WGs x 64 units (K=512: Wx1|Wh1 fused). Weights VGPR/AGPR-resident,
//    ALL register indices compile-time (rule #20).
//  - h0: full-T seq0 (u32-packed bf16 pairs), write-through stores, consumers
//    use PLAIN CACHED loads (append-only => always-cold lines => fresh; XCD L2
//    absorbs the 8-way broadcast redundancy -- the r4 insight r7/r8 lost).
//  - h1: small ring, bypass ld64 staged to LDS ONCE per WG (16B/thread),
//    issued before the h0 MFMA block so the MALL RTT hides under it.
//  - Flags: relaxed monotone counters; producer drains via __syncthreads then
//    one flag store. L1 batches h0-flag checks via lastSeen (L0 runs ahead;
//    no back-pressure needed since seq0 is full-T). L0 lockstep waits 4 flags.

#define BB 64
#define TT 2048
#define HH 256

typedef short s16x8 __attribute__((ext_vector_type(8)));
typedef float f32x4 __attribute__((ext_vector_type(4)));

__device__ inline unsigned short f2bf(float f) {
  unsigned u = __float_as_uint(f);
  u += 0x7fff + ((u >> 16) & 1);          // RNE
  return (unsigned short)(u >> 16);
}
__device__ inline float sigm(float x) { return 1.f / (1.f + __expf(-x)); }
__device__ inline float tanh_f(float x) { return 1.f - 2.f / (__expf(2.f * x) + 1.f); }

__device__ inline void st32(unsigned int* p, unsigned int v) {
  __hip_atomic_store(p, v, __ATOMIC_RELAXED, __HIP_MEMORY_SCOPE_AGENT);
}
__device__ inline void st32i(int* p, int v) {
  __hip_atomic_store(p, v, __ATOMIC_RELAXED, __HIP_MEMORY_SCOPE_AGENT);
}
__device__ inline int ld32i(const int* p) {
  return __hip_atomic_load(p, __ATOMIC_RELAXED, __HIP_MEMORY_SCOPE_AGENT);
}
__device__ inline unsigned long long ld64(const unsigned int* p) {
  return __hip_atomic_load((const unsigned long long*)p, __ATOMIC_RELAXED,
                           __HIP_MEMORY_SCOPE_AGENT);
}
__device__ inline void wait_ge(const int* p, int tgt) {
  while (ld32i(p) < tgt) __builtin_amdgcn_s_sleep(1);
}

#define MFMA(a, b, c) __builtin_amdgcn_mfma_f32_16x16x32_bf16((a), (b), (c), 0, 0, 0)

__global__ void xt_kernel(const float* __restrict__ x, float* __restrict__ xT) {
  int i = blockIdx.x * 256 + threadIdx.x;   // 131072 total
  int b = i & 63, t = i >> 6;
  xT[(size_t)t * BB + b] = x[(size_t)b * TT + t];
}

__global__ __launch_bounds__(512, 1)
void lstm_kernel(const float* __restrict__ Wx0, const float* __restrict__ Wh0,
                 const float* __restrict__ b0v,
                 const float* __restrict__ Wx1, const float* __restrict__ Wh1,
                 const float* __restrict__ b1v,
                 const float* __restrict__ xT,
                 unsigned int* __restrict__ seq0,     // [T][64][128] u32 (bf16 pairs)
                 unsigned int* __restrict__ h1ring,   // [4][2][16][128] u32
                 float* __restrict__ hmean, int* flags)
{
  __shared__ float gbuf[16][4][66];              // [row][gate][unit(pad)]
  __shared__ __align__(16) char Ab1[8192];       // L1: h1(t-1) bf16, XOR-swizzled

  const int tid  = threadIdx.x;
  const int lane = tid & 63;
  const int w    = tid >> 6;        // wave 0..7
  const int u16  = lane & 15;
  const int kgrp = lane >> 4;
  const int arow = lane & 15;
  const int bid  = blockIdx.x;

  int* f0 = flags;                  // [(g*4+wg)*16]
  int* f1 = flags + 256;            // [(g*4+q)*16]

  const int gp = w >> 2;            // gate pair: gates 2gp, 2gp+1
  const int uo = (w & 3) * 16;      // unit offset within WG's 64 units
  const int eur = tid >> 5;         // EW row 0..15
  const int eu2 = (tid & 31) * 2;   // EW local unit pair base 0..62

  if (bid < 16) {
    // ========== LAYER 0: 4 WGs/group x 64 units, K=256 ==========
    const int g = bid >> 2, wg = bid & 3;
    const int ub = wg * 64;
    s16x8 bw[2][8];                              // 64 VGPR/AGPR
#pragma unroll
    for (int nt = 0; nt < 2; ++nt)
#pragma unroll
      for (int ks = 0; ks < 8; ++ks) {
        const int col = (2 * gp + nt) * 256 + ub + uo + u16;
#pragma unroll
        for (int j = 0; j < 8; ++j)
          bw[nt][ks][j] = (short)f2bf(Wh0[(size_t)(ks * 32 + kgrp * 8 + j) * 1024 + col]);
      }
    float bE[4][2], xE[4][2];
#pragma unroll
    for (int ga = 0; ga < 4; ++ga)
#pragma unroll
      for (int uu = 0; uu < 2; ++uu) {
        const int c = ga * 256 + ub + eu2 + uu;
        bE[ga][uu] = b0v[c]; xE[ga][uu] = Wx0[c];
      }
    int* myf = &f0[(g * 4 + wg) * 16];
    float cL[2] = {0.f, 0.f};

    for (int t = 0; t < TT; ++t) {
      if (t > 0 && tid < 4) wait_ge(&f0[(g * 4 + tid) * 16], t);
      __syncthreads();

      f32x4 acc0 = {0,0,0,0}, acc1 = {0,0,0,0};
      if (t > 0) {
        // h(t-1): plain cached loads from append-only seq0 (cold lines => fresh)
        const unsigned int* sp = seq0 + ((size_t)(t - 1) * BB + g * 16 + arow) * 128;
        s16x8 a[8];
#pragma unroll
        for (int ks = 0; ks < 8; ++ks) a[ks] = *(const s16x8*)(sp + ks * 16 + kgrp * 4);
#pragma unroll
        for (int ks = 0; ks < 8; ++ks) {
          acc0 = MFMA(a[ks], bw[0][ks], acc0);
          acc1 = MFMA(a[ks], bw[1][ks], acc1);
        }
      }
#pragma unroll
      for (int r = 0; r < 4; ++r) {
        gbuf[kgrp * 4 + r][2 * gp + 0][uo + u16] = acc0[r];
        gbuf[kgrp * 4 + r][2 * gp + 1][uo + u16] = acc1[r];
      }
      __syncthreads();

      const float xval = xT[(size_t)t * BB + g * 16 + eur];
      unsigned short hb[2];
#pragma unroll
      for (int uu = 0; uu < 2; ++uu) {
        const int u = eu2 + uu;
        const float gi = gbuf[eur][0][u] + bE[0][uu] + xval * xE[0][uu];
        const float gf = gbuf[eur][1][u] + bE[1][uu] + xval * xE[1][uu];
        const float gg = gbuf[eur][2][u] + bE[2][uu] + xval * xE[2][uu];
        const float go = gbuf[eur][3][u] + bE[3][uu] + xval * xE[3][uu];
        cL[uu] = sigm(gf) * cL[uu] + sigm(gi) * tanh_f(gg);
        const float hv = sigm(go) * tanh_f(cL[uu]);
        hb[uu] = f2bf(hv);
      }
      st32(seq0 + ((size_t)t * BB + g * 16 + eur) * 128 + ((ub + eu2) >> 1),
           (unsigned int)hb[0] | ((unsigned int)hb[1] << 16));
      __syncthreads();   // drains vmcnt: write-through stores acked
      if (tid == 0) st32i(myf, t + 1);
    }
  } else {
    // ========== LAYER 1: 4 WGs/group x 64 units, K=512 (Wx1|Wh1) ==========
    const int idx = bid - 16, g = idx >> 2, q = idx & 3;
    const int ub = q * 64;
    s16x8 bw[2][16];                             // 128 VGPR/AGPR, static idx only
#pragma unroll
    for (int nt = 0; nt < 2; ++nt)
#pragma unroll
      for (int ks = 0; ks < 16; ++ks) {
        const int col = (2 * gp + nt) * 256 + ub + uo + u16;
#pragma unroll
        for (int j = 0; j < 8; ++j) {
          const int k = (ks & 7) * 32 + kgrp * 8 + j;
          bw[nt][ks][j] = (short)f2bf((ks < 8) ? Wx1[(size_t)k * 1024 + col]
                                               : Wh1[(size_t)k * 1024 + col]);
        }
      }
    float bE[4][2];
#pragma unroll
    for (int ga = 0; ga < 4; ++ga)
#pragma unroll
      for (int uu = 0; uu < 2; ++uu)
        bE[ga][uu] = b1v[ga * 256 + ub + eu2 + uu];
    int* myf = &f1[(g * 4 + q) * 16];
    unsigned int* hr = h1ring + (size_t)g * 4096;   // [2][16][128] u32
    const int srow = tid >> 5, sc4 = (tid & 31) * 4;
    int seen = 0;                                // lastSeen h0 flag (tid<4)
    float cL[2] = {0.f, 0.f}, hs[2] = {0.f, 0.f};

    for (int t = 0; t < TT; ++t) {
      if (tid < 4) {                             // h0(t) ready? batched via lastSeen
        if (seen <= t) {
          do { seen = ld32i(&f0[(g * 4 + tid) * 16]);
               if (seen <= t) __builtin_amdgcn_s_sleep(1); } while (seen <= t);
        }
      } else if (t > 0 && tid < 7) {             // 3 peer flags (lockstep)
        int qq = tid - 4; qq += (qq >= q);
        wait_ge(&f1[(g * 4 + qq) * 16], t);
      }
      __syncthreads();

      // issue h1(t-1) bypass loads FIRST (RTT hides under h0 MFMAs)
      unsigned long long q0 = 0, q1 = 0;
      if (t > 0) {
        const unsigned int* sb = hr + ((t - 1) & 1) * 2048 + srow * 128 + sc4;
        q0 = ld64(sb); q1 = ld64(sb + 2);
      }
      // h0(t) half: plain cached loads + 16 MFMAs
      f32x4 acc0 = {0,0,0,0}, acc1 = {0,0,0,0};
      {
        const unsigned int* sp = seq0 + ((size_t)t * BB + g * 16 + arow) * 128;
        s16x8 a[8];
#pragma unroll
        for (int ks = 0; ks < 8; ++ks) a[ks] = *(const s16x8*)(sp + ks * 16 + kgrp * 4);
#pragma unroll
        for (int ks = 0; ks < 8; ++ks) {
          acc0 = MFMA(a[ks], bw[0][ks], acc0);
          acc1 = MFMA(a[ks], bw[1][ks], acc1);
        }
      }
      if (t > 0) {
        // stage h1 to LDS once per WG (16B/thread), then 16 MFMAs
        const unsigned int w0 = (unsigned)(q0 & 0xFFFFFFFFu), w1 = (unsigned)(q0 >> 32);
        const unsigned int w2 = (unsigned)(q1 & 0xFFFFFFFFu), w3 = (unsigned)(q1 >> 32);
        *(uint4*)(Ab1 + ((srow * 512 + (tid & 31) * 16) ^ ((srow & 7) << 4))) =
            (uint4){w0, w1, w2, w3};
        __syncthreads();
        s16x8 a[8];
#pragma unroll
        for (int kk = 0; kk < 8; ++kk)
          a[kk] = *(const s16x8*)(Ab1 + ((arow * 512 + (kk * 32 + kgrp * 8) * 2) ^ ((arow & 7) << 4)));
#pragma unroll
        for (int kk = 0; kk < 8; ++kk) {
          acc0 = MFMA(a[kk], bw[0][8 + kk], acc0);
          acc1 = MFMA(a[kk], bw[1][8 + kk], acc1);
        }
      }
#pragma unroll
      for (int r = 0; r < 4; ++r) {
        gbuf[kgrp * 4 + r][2 * gp + 0][uo + u16] = acc0[r];
        gbuf[kgrp * 4 + r][2 * gp + 1][uo + u16] = acc1[r];
      }
      __syncthreads();

      unsigned short hb[2];
#pragma unroll
      for (int uu = 0; uu < 2; ++uu) {
        const int u = eu2 + uu;
        const float gi = gbuf[eur][0][u] + bE[0][uu];
        const float gf = gbuf[eur][1][u] + bE[1][uu];
        const float gg = gbuf[eur][2][u] + bE[2][uu];
        const float go = gbuf[eur][3][u] + bE[3][uu];
        cL[uu] = sigm(gf) * cL[uu] + sigm(gi) * tanh_f(gg);
        const float hv = sigm(go) * tanh_f(cL[uu]);
        hs[uu] += hv;
        hb[uu] = f2bf(hv);
      }
      st32(hr + (t & 1) * 2048 + eur * 128 + ((ub + eu2) >> 1),
           (unsigned int)hb[0] | ((unsigned int)hb[1] << 16));
      __syncthreads();   // drains vmcnt before flag
      if (tid == 0) st32i(myf, t + 1);
    }
#pragma unroll
    for (int uu = 0; uu < 2; ++uu)
      hmean[(size_t)(g * 16 + eur) * HH + ub + eu2 + uu] = hs[uu] * (1.f / TT);
  }
}

__global__ __launch_bounds__(256)
void mlp_kernel(const float* __restrict__ theta, const float* __restrict__ Wtp,
                const float* __restrict__ btp, const float* __restrict__ Wl1,
                const float* __restrict__ bl1, const float* __restrict__ Wl2,
                const float* __restrict__ bl2, const float* __restrict__ Wo,
                const float* __restrict__ bo, const float* __restrict__ hmean,
                float* __restrict__ out)
{
  const int b = blockIdx.x;
  const int j = threadIdx.x;
  __shared__ float z[2 * HH];
  __shared__ float z1s[HH];
  __shared__ float red[256];

  float tp = btp[j];
#pragma unroll
  for (int d = 0; d < 5; ++d) tp += theta[b * 5 + d] * Wtp[d * HH + j];
  z[j] = hmean[(size_t)b * HH + j];
  z[HH + j] = tp;
  __syncthreads();

  float a1 = bl1[j];
  for (int k = 0; k < 2 * HH; ++k) a1 += z[k] * Wl1[(size_t)k * 256 + j];
  a1 = (a1 > 0.f) ? a1 : (__expf(a1) - 1.f);
  z1s[j] = a1;
  __syncthreads();

  float a2 = bl2[j];
  for (int k = 0; k < HH; ++k) a2 += z1s[k] * Wl2[(size_t)k * 256 + j];
  a2 = (a2 > 0.f) ? a2 : (__expf(a2) - 1.f);
  red[j] = a2 * Wo[j];
  __syncthreads();
  for (int s = 128; s > 0; s >>= 1) {
    if (j < s) red[j] += red[j + s];
    __syncthreads();
  }
  if (j == 0) out[b] = red[0] + bo[0];
}

extern "C" void kernel_launch(void* const* d_in, const int* in_sizes, int n_in,
                              void* d_out, int out_size, void* d_ws, size_t ws_size,
                              hipStream_t stream) {
  const float* x    = (const float*)d_in[0];
  const float* theta= (const float*)d_in[1];
  const float* Wx0  = (const float*)d_in[2];
  const float* Wh0  = (const float*)d_in[3];
  const float* b0   = (const float*)d_in[4];
  const float* Wx1  = (const float*)d_in[5];
  const float* Wh1  = (const float*)d_in[6];
  const float* b1   = (const float*)d_in[7];
  const float* Wtp  = (const float*)d_in[8];
  const float* btp  = (const float*)d_in[9];
  const float* Wl1  = (const float*)d_in[10];
  const float* bl1  = (const float*)d_in[11];
  const float* Wl2  = (const float*)d_in[12];
  const float* bl2  = (const float*)d_in[13];
  const float* Wo   = (const float*)d_in[14];
  const float* bo   = (const float*)d_in[15];

  // ws: flags 8KB (memset) | h1ring u32 4x[2][16][128] 64KB | hmean 64KB
  //     | xT 512KB | seq0 u32 [T][64][128] 64MB (append-only; no init needed:
  //     consumers only read entries whose flags were set THIS launch)
  char* ws = (char*)d_ws;
  int* flags            = (int*)ws;
  unsigned int* h1ring  = (unsigned int*)(ws + 8192);
  float* hmean          = (float*)(ws + 8192 + 65536);
  float* xT             = (float*)(ws + 8192 + 65536 + 65536);
  unsigned int* seq0    = (unsigned int*)(ws + 8192 + 65536 + 65536 + 524288);
  const size_t WS_NEED = 8192ull + 65536 + 65536 + 524288 + (size_t)TT * BB * 128 * 4ull;
  if (ws_size < WS_NEED) return;

  hipMemsetAsync(d_ws, 0, 8192, stream);   // flags only

  xt_kernel<<<dim3((BB * TT) / 256), dim3(256), 0, stream>>>(x, xT);
  lstm_kernel<<<dim3(32), dim3(512), 0, stream>>>(
      Wx0, Wh0, b0, Wx1, Wh1, b1, xT, seq0, h1ring, hmean, flags);
  mlp_kernel<<<dim3(BB), dim3(256), 0, stream>>>(
      theta, Wtp, btp, Wl1, bl1, Wl2, bl2, Wo, bo, hmean, (float*)d_out);
}

// Round 10
// 6187.303 us; speedup vs baseline: 3.7930x; 1.3567x over previous
//
#include <hip/hip_runtime.h>
#include <hip/hip_bf16.h>

// LSTMModel_with_theta: B=64, T=2048, H=256, 2-layer LSTM -> mean_t -> MLP.
//
// Round 10: consolidation. One exposed fabric hop per recurrence step.
//  - Tagged self-sync data everywhere: u32 = (tag=t+1)<<16 | h_bf16. No flags,
//    no producer vmcnt drains (r5/r7). Consumers tag-check prefetched data.
//  - Once-per-WG cooperative bypass staging into LDS (r9) -- kills r7's
//    per-wave redundant MALL reads.
//  - Prefetch-early / check-late (r8 mechanism, without doubling WG work):
//    L0 partner poll overlaps own-half MFMAs; L1 h1 prefetch issued right
//    after publish, checked ~1200cy later; L1 h0 always ready (L0 runs ahead
//    under coarse back-pressure every 8 steps).
//  - L0: 2 WGs/group x 128 units (r7 phase-layout bw[32], static indices).
//    L1: 4 WGs/group x 64 units, K=512 fused (r9 bw[2][16], static indices).
//  - Barriers: s_barrier + lgkmcnt(0) only (global tagged stores never drained).

#define BB 64
#define TT 2048
#define HH 256
#define D0 16
#define D1 4

typedef short s16x8 __attribute__((ext_vector_type(8)));
typedef float f32x4 __attribute__((ext_vector_type(4)));

__device__ inline unsigned short f2bf(float f) {
  unsigned u = __float_as_uint(f);
  u += 0x7fff + ((u >> 16) & 1);          // RNE
  return (unsigned short)(u >> 16);
}
__device__ inline float sigm(float x) { return 1.f / (1.f + __expf(-x)); }
__device__ inline float tanh_f(float x) { return 1.f - 2.f / (__expf(2.f * x) + 1.f); }

__device__ inline unsigned long long ld64(const unsigned int* p) {
  return __hip_atomic_load((const unsigned long long*)p, __ATOMIC_RELAXED,
                           __HIP_MEMORY_SCOPE_AGENT);
}
__device__ inline void st32(unsigned int* p, unsigned int v) {
  __hip_atomic_store(p, v, __ATOMIC_RELAXED, __HIP_MEMORY_SCOPE_AGENT);
}
__device__ inline void st32i(int* p, int v) {
  __hip_atomic_store(p, v, __ATOMIC_RELAXED, __HIP_MEMORY_SCOPE_AGENT);
}
__device__ inline int ld32i(const int* p) {
  return __hip_atomic_load(p, __ATOMIC_RELAXED, __HIP_MEMORY_SCOPE_AGENT);
}
// barrier WITHOUT vmcnt drain: LDS-fence only
__device__ inline void wg_bar() {
  asm volatile("s_waitcnt lgkmcnt(0)" ::: "memory");
  __builtin_amdgcn_sched_barrier(0);
  __builtin_amdgcn_s_barrier();
  __builtin_amdgcn_sched_barrier(0);
}

#define MFMA(a, b, c) __builtin_amdgcn_mfma_f32_16x16x32_bf16((a), (b), (c), 0, 0, 0)

__global__ void xt_kernel(const float* __restrict__ x, float* __restrict__ xT) {
  int i = blockIdx.x * 256 + threadIdx.x;   // 131072 total
  int b = i & 63, t = i >> 6;
  xT[(size_t)t * BB + b] = x[(size_t)b * TT + t];
}

__global__ __launch_bounds__(512, 1)
void lstm_kernel(const float* __restrict__ Wx0, const float* __restrict__ Wh0,
                 const float* __restrict__ b0v,
                 const float* __restrict__ Wx1, const float* __restrict__ Wh1,
                 const float* __restrict__ b1v,
                 const float* __restrict__ xT,
                 unsigned int* __restrict__ seqring,   // [4][D0][16][256] tagged u32
                 unsigned int* __restrict__ h1ring,    // [4][D1][16][256] tagged u32
                 float* __restrict__ hmean, int* prog)
{
  __shared__ __align__(16) char Ab [8192];       // [16 rows][256 units] bf16, swizzled
  __shared__ __align__(16) char Ab1[8192];       // L1: h1(t-1)
  __shared__ float gbuf[16][4][66];              // L1 gate gather

  const int tid  = threadIdx.x;
  const int lane = tid & 63;
  const int w    = tid >> 6;        // wave 0..7
  const int u16  = lane & 15;
  const int kgrp = lane >> 4;
  const int arow = lane & 15;
  const int bid  = blockIdx.x;

  if (bid < 8) {
    // ========== LAYER 0: 2 WGs/group x 128 units, K=256 ==========
    const int g = bid >> 1, ho = bid & 1, po = 1 - ho;
    const int U = ho * 128 + w * 16 + u16;       // lane's unit (all 4 gates)
    // bw by PHASE (static reg indices): [n*8+0..3]=own ks, [n*8+4..7]=partner ks
    s16x8 bw[32];
#pragma unroll
    for (int n = 0; n < 4; ++n)
#pragma unroll
      for (int ph = 0; ph < 2; ++ph)
#pragma unroll
        for (int i = 0; i < 4; ++i) {
          const int ks = (ph == 0 ? ho : po) * 4 + i;   // runtime, address-only
          const int col = n * 256 + U;
#pragma unroll
          for (int j = 0; j < 8; ++j)
            bw[n * 8 + ph * 4 + i][j] =
                (short)f2bf(Wh0[(size_t)(ks * 32 + kgrp * 8 + j) * 1024 + col]);
        }
    float bE[4], xE[4];
#pragma unroll
    for (int n = 0; n < 4; ++n) { bE[n] = b0v[n * 256 + U]; xE[n] = Wx0[n * 256 + U]; }

    unsigned int* sr = seqring + (size_t)g * D0 * 4096;
    const int srow = tid >> 5, spc = (tid & 31) * 4;    // partner stage: 4 u32/thread
    float cL[4] = {0.f, 0.f, 0.f, 0.f};
    unsigned long long pq0 = 0, pq1 = 0;                // prefetched partner h

    for (int t = 0; t < TT; ++t) {
      if ((t & 7) == 0 && t >= 16 && tid < 4)           // L1 back-pressure (coarse)
        while (ld32i(&prog[(g * 4 + tid) * 16]) < t - 8) __builtin_amdgcn_s_sleep(8);
      wg_bar();   // top: EW(t-1) LDS writes visible; back-pressure done

      f32x4 acc[4] = {{0,0,0,0},{0,0,0,0},{0,0,0,0},{0,0,0,0}};
      if (t > 0) {
        // own-half MFMAs from LDS (overlap partner poll)
        s16x8 ao[4];
#pragma unroll
        for (int i = 0; i < 4; ++i) {
          const int ks = ho * 4 + i;
          ao[i] = *(const s16x8*)(Ab + ((arow * 512 + (ks * 32 + kgrp * 8) * 2) ^ ((arow & 7) << 4)));
        }
#pragma unroll
        for (int i = 0; i < 4; ++i)
#pragma unroll
          for (int n = 0; n < 4; ++n) acc[n] = MFMA(ao[i], bw[n * 8 + i], acc[n]);
        // check prefetched partner h(t-1); retry until tags match
        const unsigned int* sb = sr + ((t - 1) & (D0 - 1)) * 4096 + srow * 256 + po * 128 + spc;
        const unsigned int tg = (unsigned int)t;
        unsigned long long q0 = pq0, q1 = pq1;
        for (;;) {
          const bool ok = (((q0 >> 16) & 0xFFFFu) == tg) & ((unsigned)(q0 >> 48) == tg) &
                          (((q1 >> 16) & 0xFFFFu) == tg) & ((unsigned)(q1 >> 48) == tg);
          if (__all(ok)) break;
          __builtin_amdgcn_s_sleep(1);
          q0 = ld64(sb); q1 = ld64(sb + 2);
        }
        const unsigned int lo = (unsigned)(q0 & 0xFFFF) | (((unsigned)(q0 >> 32) & 0xFFFF) << 16);
        const unsigned int hi = (unsigned)(q1 & 0xFFFF) | (((unsigned)(q1 >> 32) & 0xFFFF) << 16);
        *(uint2*)(Ab + ((srow * 512 + (po * 128 + spc) * 2) ^ ((srow & 7) << 4))) = (uint2){lo, hi};
      }
      wg_bar();   // partner staged
      if (t > 0) {
        s16x8 ap[4];
#pragma unroll
        for (int i = 0; i < 4; ++i) {
          const int ks = po * 4 + i;
          ap[i] = *(const s16x8*)(Ab + ((arow * 512 + (ks * 32 + kgrp * 8) * 2) ^ ((arow & 7) << 4)));
        }
#pragma unroll
        for (int i = 0; i < 4; ++i)
#pragma unroll
          for (int n = 0; n < 4; ++n) acc[n] = MFMA(ap[i], bw[n * 8 + 4 + i], acc[n]);
      }
      // EW per-lane; publish tagged (no drain) + own-half h into LDS
      float xr[4];
#pragma unroll
      for (int r = 0; r < 4; ++r) xr[r] = xT[(size_t)t * BB + g * 16 + kgrp * 4 + r];
      const unsigned int tagw = (unsigned)(t + 1) << 16;
#pragma unroll
      for (int r = 0; r < 4; ++r) {
        const int row = kgrp * 4 + r;
        const float gi = acc[0][r] + bE[0] + xr[r] * xE[0];
        const float gf = acc[1][r] + bE[1] + xr[r] * xE[1];
        const float gg = acc[2][r] + bE[2] + xr[r] * xE[2];
        const float go = acc[3][r] + bE[3] + xr[r] * xE[3];
        cL[r] = sigm(gf) * cL[r] + sigm(gi) * tanh_f(gg);
        const float hv = sigm(go) * tanh_f(cL[r]);
        const unsigned short hb = f2bf(hv);
        st32(sr + (t & (D0 - 1)) * 4096 + row * 256 + U, tagw | hb);
        *(unsigned short*)(Ab + ((row * 512 + U * 2) ^ ((row & 7) << 4))) = hb;
      }
      // prefetch partner h(t) (flies until next step's check)
      {
        const unsigned int* sb = sr + (t & (D0 - 1)) * 4096 + srow * 256 + po * 128 + spc;
        pq0 = ld64(sb); pq1 = ld64(sb + 2);
      }
    }
  } else {
    // ========== LAYER 1: 4 WGs/group x 64 units, K=512 (Wx1|Wh1) ==========
    const int idx = bid - 8, g = idx >> 2, q = idx & 3;
    const int gp = w >> 2;            // gate pair
    const int uo = (w & 3) * 16;      // unit offset in WG's 64
    const int ub = q * 64;
    s16x8 bw[2][16];                  // static idx only (r9-proven)
#pragma unroll
    for (int nt = 0; nt < 2; ++nt)
#pragma unroll
      for (int ks = 0; ks < 16; ++ks) {
        const int col = (2 * gp + nt) * 256 + ub + uo + u16;
#pragma unroll
        for (int j = 0; j < 8; ++j) {
          const int k = (ks & 7) * 32 + kgrp * 8 + j;
          bw[nt][ks][j] = (short)f2bf((ks < 8) ? Wx1[(size_t)k * 1024 + col]
                                               : Wh1[(size_t)k * 1024 + col]);
        }
      }
    const int eur = tid >> 5, eu2 = (tid & 31) * 2;
    float bE[4][2];
#pragma unroll
    for (int ga = 0; ga < 4; ++ga)
#pragma unroll
      for (int uu = 0; uu < 2; ++uu)
        bE[ga][uu] = b1v[ga * 256 + ub + eu2 + uu];

    unsigned int* sr = seqring + (size_t)g * D0 * 4096;
    unsigned int* hr = h1ring  + (size_t)g * D1 * 4096;
    const int srow = tid >> 5, sc8 = (tid & 31) * 8;    // stage: 8 u32/thread
    float cL[2] = {0.f, 0.f}, hs[2] = {0.f, 0.f};
    unsigned long long qh0[4], qh1[4];

    // prologue: prefetch h0(0)
    {
      const unsigned int* sb = sr + srow * 256 + sc8;
#pragma unroll
      for (int i = 0; i < 4; ++i) qh0[i] = ld64(sb + i * 2);
    }

    for (int t = 0; t < TT; ++t) {
      if ((t & 3) == 3 && tid == 0) st32i(&prog[(g * 4 + q) * 16], t);
      // ---- h0(t): check prefetched (L0 runs ahead -> first check passes) ----
      {
        const unsigned int* sb = sr + (t & (D0 - 1)) * 4096 + srow * 256 + sc8;
        const unsigned int tg = (unsigned int)(t + 1);
        for (;;) {
          bool ok = true;
#pragma unroll
          for (int i = 0; i < 4; ++i)
            ok &= (((qh0[i] >> 16) & 0xFFFFu) == tg) & ((unsigned)(qh0[i] >> 48) == tg);
          if (__all(ok)) break;
          __builtin_amdgcn_s_sleep(1);
#pragma unroll
          for (int i = 0; i < 4; ++i) qh0[i] = ld64(sb + i * 2);
        }
        unsigned int wv[4];
#pragma unroll
        for (int i = 0; i < 4; ++i)
          wv[i] = (unsigned)(qh0[i] & 0xFFFF) | (((unsigned)(qh0[i] >> 32) & 0xFFFF) << 16);
        *(uint4*)(Ab + ((srow * 512 + sc8 * 2) ^ ((srow & 7) << 4))) =
            (uint4){wv[0], wv[1], wv[2], wv[3]};
      }
      wg_bar();   // h0 staged
      f32x4 acc0 = {0,0,0,0}, acc1 = {0,0,0,0};
      {
        s16x8 a[8];
#pragma unroll
        for (int ks = 0; ks < 8; ++ks)
          a[ks] = *(const s16x8*)(Ab + ((arow * 512 + (ks * 32 + kgrp * 8) * 2) ^ ((arow & 7) << 4)));
#pragma unroll
        for (int ks = 0; ks < 8; ++ks) {
          acc0 = MFMA(a[ks], bw[0][ks], acc0);
          acc1 = MFMA(a[ks], bw[1][ks], acc1);
        }
      }
      // ---- h1(t-1): check prefetched (issued after publish at t-1) ----
      if (t > 0) {
        const unsigned int* sb = hr + ((t - 1) & (D1 - 1)) * 4096 + srow * 256 + sc8;
        const unsigned int tg = (unsigned int)t;
        for (;;) {
          bool ok = true;
#pragma unroll
          for (int i = 0; i < 4; ++i)
            ok &= (((qh1[i] >> 16) & 0xFFFFu) == tg) & ((unsigned)(qh1[i] >> 48) == tg);
          if (__all(ok)) break;
          __builtin_amdgcn_s_sleep(1);
#pragma unroll
          for (int i = 0; i < 4; ++i) qh1[i] = ld64(sb + i * 2);
        }
        unsigned int wv[4];
#pragma unroll
        for (int i = 0; i < 4; ++i)
          wv[i] = (unsigned)(qh1[i] & 0xFFFF) | (((unsigned)(qh1[i] >> 32) & 0xFFFF) << 16);
        *(uint4*)(Ab1 + ((srow * 512 + sc8 * 2) ^ ((srow & 7) << 4))) =
            (uint4){wv[0], wv[1], wv[2], wv[3]};
      }
      wg_bar();   // h1 staged
      if (t > 0) {
        s16x8 a[8];
#pragma unroll
        for (int kk = 0; kk < 8; ++kk)
          a[kk] = *(const s16x8*)(Ab1 + ((arow * 512 + (kk * 32 + kgrp * 8) * 2) ^ ((arow & 7) << 4)));
#pragma unroll
        for (int kk = 0; kk < 8; ++kk) {
          acc0 = MFMA(a[kk], bw[0][8 + kk], acc0);
          acc1 = MFMA(a[kk], bw[1][8 + kk], acc1);
        }
      }
#pragma unroll
      for (int r = 0; r < 4; ++r) {
        gbuf[kgrp * 4 + r][2 * gp + 0][uo + u16] = acc0[r];
        gbuf[kgrp * 4 + r][2 * gp + 1][uo + u16] = acc1[r];
      }
      wg_bar();   // gates gathered

      unsigned short hb[2];
#pragma unroll
      for (int uu = 0; uu < 2; ++uu) {
        const int u = eu2 + uu;
        const float gi = gbuf[eur][0][u] + bE[0][uu];
        const float gf = gbuf[eur][1][u] + bE[1][uu];
        const float gg = gbuf[eur][2][u] + bE[2][uu];
        const float go = gbuf[eur][3][u] + bE[3][uu];
        cL[uu] = sigm(gf) * cL[uu] + sigm(gi) * tanh_f(gg);
        const float hv = sigm(go) * tanh_f(cL[uu]);
        hs[uu] += hv;
        hb[uu] = f2bf(hv);
      }
      const unsigned int tagw = (unsigned)(t + 1) << 16;
      st32(hr + (t & (D1 - 1)) * 4096 + eur * 256 + ub + eu2,     tagw | hb[0]);
      st32(hr + (t & (D1 - 1)) * 4096 + eur * 256 + ub + eu2 + 1, tagw | hb[1]);
      // ---- prefetch for next step (fly during next h0 section) ----
      {
        const unsigned int* sb = sr + ((t + 1) & (D0 - 1)) * 4096 + srow * 256 + sc8;
#pragma unroll
        for (int i = 0; i < 4; ++i) qh0[i] = ld64(sb + i * 2);
        const unsigned int* hb2 = hr + (t & (D1 - 1)) * 4096 + srow * 256 + sc8;
#pragma unroll
        for (int i = 0; i < 4; ++i) qh1[i] = ld64(hb2 + i * 2);
      }
    }
#pragma unroll
    for (int uu = 0; uu < 2; ++uu)
      hmean[(size_t)(g * 16 + eur) * HH + ub + eu2 + uu] = hs[uu] * (1.f / TT);
  }
}

__global__ __launch_bounds__(256)
void mlp_kernel(const float* __restrict__ theta, const float* __restrict__ Wtp,
                const float* __restrict__ btp, const float* __restrict__ Wl1,
                const float* __restrict__ bl1, const float* __restrict__ Wl2,
                const float* __restrict__ bl2, const float* __restrict__ Wo,
                const float* __restrict__ bo, const float* __restrict__ hmean,
                float* __restrict__ out)
{
  const int b = blockIdx.x;
  const int j = threadIdx.x;
  __shared__ float z[2 * HH];
  __shared__ float z1s[HH];
  __shared__ float red[256];

  float tp = btp[j];
#pragma unroll
  for (int d = 0; d < 5; ++d) tp += theta[b * 5 + d] * Wtp[d * HH + j];
  z[j] = hmean[(size_t)b * HH + j];
  z[HH + j] = tp;
  __syncthreads();

  float a1 = bl1[j];
  for (int k = 0; k < 2 * HH; ++k) a1 += z[k] * Wl1[(size_t)k * 256 + j];
  a1 = (a1 > 0.f) ? a1 : (__expf(a1) - 1.f);
  z1s[j] = a1;
  __syncthreads();

  float a2 = bl2[j];
  for (int k = 0; k < HH; ++k) a2 += z1s[k] * Wl2[(size_t)k * 256 + j];
  a2 = (a2 > 0.f) ? a2 : (__expf(a2) - 1.f);
  red[j] = a2 * Wo[j];
  __syncthreads();
  for (int s = 128; s > 0; s >>= 1) {
    if (j < s) red[j] += red[j + s];
    __syncthreads();
  }
  if (j == 0) out[b] = red[0] + bo[0];
}

extern "C" void kernel_launch(void* const* d_in, const int* in_sizes, int n_in,
                              void* d_out, int out_size, void* d_ws, size_t ws_size,
                              hipStream_t stream) {
  const float* x    = (const float*)d_in[0];
  const float* theta= (const float*)d_in[1];
  const float* Wx0  = (const float*)d_in[2];
  const float* Wh0  = (const float*)d_in[3];
  const float* b0   = (const float*)d_in[4];
  const float* Wx1  = (const float*)d_in[5];
  const float* Wh1  = (const float*)d_in[6];
  const float* b1   = (const float*)d_in[7];
  const float* Wtp  = (const float*)d_in[8];
  const float* btp  = (const float*)d_in[9];
  const float* Wl1  = (const float*)d_in[10];
  const float* bl1  = (const float*)d_in[11];
  const float* Wl2  = (const float*)d_in[12];
  const float* bl2  = (const float*)d_in[13];
  const float* Wo   = (const float*)d_in[14];
  const float* bo   = (const float*)d_in[15];

  // ws: prog 8KB | seqring [4][16][16][256] u32 1MB | h1ring [4][4][16][256] u32 256KB
  //     | hmean 64KB | xT 512KB.  prog+rings memset each launch (tag 0 never valid).
  char* ws = (char*)d_ws;
  int* prog             = (int*)ws;
  unsigned int* seqring = (unsigned int*)(ws + 8192);
  unsigned int* h1ring  = (unsigned int*)(ws + 8192 + 1048576);
  float* hmean          = (float*)(ws + 8192 + 1048576 + 262144);
  float* xT             = (float*)(ws + 8192 + 1048576 + 262144 + 65536);
  const size_t WS_NEED = 8192ull + 1048576 + 262144 + 65536 + 524288;
  if (ws_size < WS_NEED) return;

  hipMemsetAsync(d_ws, 0, 8192 + 1048576 + 262144, stream);

  xt_kernel<<<dim3((BB * TT) / 256), dim3(256), 0, stream>>>(x, xT);
  lstm_kernel<<<dim3(24), dim3(512), 0, stream>>>(
      Wx0, Wh0, b0, Wx1, Wh1, b1, xT, seqring, h1ring, hmean, prog);
  mlp_kernel<<<dim3(BB), dim3(256), 0, stream>>>(
      theta, Wtp, btp, Wl1, bl1, Wl2, bl2, Wo, bo, hmean, (float*)d_out);
}